// Round 1
// 1662.464 us; speedup vs baseline: 1.3007x; 1.3007x over previous
//
#include <hip/hip_runtime.h>

// Problem constants
#define D_  1024
#define H_  1024
#define H2_ 512
#define M_  15
#define B_  8192

typedef __attribute__((ext_vector_type(4))) float f32x4;
typedef __attribute__((ext_vector_type(8))) short short8;

__device__ __forceinline__ unsigned short f2bf(float f) {
  unsigned int u = __float_as_uint(f);
  u += 0x7fffu + ((u >> 16) & 1u);   // round-to-nearest-even
  return (unsigned short)(u >> 16);
}
__device__ __forceinline__ float bf2f(unsigned int h) {
  return __uint_as_float(h << 16);
}
__device__ __forceinline__ float gelu_exact(float x) {
  return 0.5f * x * (1.0f + erff(x * 0.70710678118654752440f));
}

// ---------------- fp32 -> bf16 cast (vectorized) ----------------
__global__ void cast_f32_bf16(const float* __restrict__ in, unsigned short* __restrict__ out, int n4) {
  int i = blockIdx.x * blockDim.x + threadIdx.x;
  if (i >= n4) return;
  float4 v = ((const float4*)in)[i];
  ushort4 o;
  o.x = f2bf(v.x); o.y = f2bf(v.y); o.z = f2bf(v.z); o.w = f2bf(v.w);
  ((ushort4*)out)[i] = o;
}

// ---------------- fp32 [K,N] -> bf16 [N,K] transpose-cast ----------------
// grid (K/32, N/32, M), block (32,8)
__global__ void transpose_cast(const float* __restrict__ in, unsigned short* __restrict__ out,
                               int K, int N) {
  __shared__ float t[32][33];
  const size_t mo = (size_t)blockIdx.z * K * N;
  in  += mo;
  out += mo;
  const int k0 = blockIdx.x * 32, n0 = blockIdx.y * 32;
  const int tx = threadIdx.x, ty = threadIdx.y;
#pragma unroll
  for (int j = 0; j < 32; j += 8)
    t[ty + j][tx] = in[(size_t)(k0 + ty + j) * N + (n0 + tx)];
  __syncthreads();
#pragma unroll
  for (int j = 0; j < 32; j += 8)
    out[(size_t)(n0 + ty + j) * K + (k0 + tx)] = f2bf(t[tx][ty + j]);
}

// ---------------- Grouped GEMM: C[z][r,c] = sum_k A[z][r,k]*Bt[z][c,k] + bias[z][c] -------
// A: bf16 [Mrows,K] (+ z*sA), Bt: bf16 [N,K] (+ z*sB), bias fp32 [N] (+ z*sBias).
// EPI 0: store bf16(v).  EPI 1: store bf16(gelu(v)).  EPI 2: store fp32(sigmoid(v)).
// 128x128 tile, BK=64, 256 threads (4 waves, 2x2 of 64x64), mfma 16x16x32 bf16.
template <int EPI>
__launch_bounds__(256, 3)
__global__ void gemm_bt(const unsigned short* __restrict__ A, const unsigned short* __restrict__ Bt,
                        const float* __restrict__ bias, void* __restrict__ Cout,
                        int Mrows, int N, int K,
                        long sA, long sB, long sBias, long sC) {
  __shared__ __align__(16) unsigned short As[128 * 64];
  __shared__ __align__(16) unsigned short Bs[128 * 64];
  const int mz = blockIdx.z;
  A    += (size_t)mz * sA;
  Bt   += (size_t)mz * sB;
  bias += (size_t)mz * sBias;

  const int tid  = threadIdx.x;
  const int w    = tid >> 6;
  const int lane = tid & 63;
  const int row0 = blockIdx.x * 128;
  const int col0 = blockIdx.y * 128;

  f32x4 acc[4][4];
#pragma unroll
  for (int i = 0; i < 4; ++i)
#pragma unroll
    for (int j = 0; j < 4; ++j) acc[i][j] = (f32x4){0.f, 0.f, 0.f, 0.f};

  const int wm = w >> 1, wn = w & 1;
  const int mrow = lane & 15;
  const int kq   = (lane >> 4) << 3;

  for (int k0 = 0; k0 < K; k0 += 64) {
    __syncthreads();
#pragma unroll
    for (int i = 0; i < 4; ++i) {
      const int c  = i * 256 + tid;
      const int m  = c >> 3;          // tile row (0..127)
      const int kk = (c & 7) << 3;    // k offset (0,8,..,56)
      const unsigned short* gA = A  + (size_t)(row0 + m) * K + (k0 + kk);
      const unsigned short* gB = Bt + (size_t)(col0 + m) * K + (k0 + kk);
      const int ldsoff = (i * 256 + w * 64) * 8;  // elements; wave-uniform base
      __builtin_amdgcn_global_load_lds((const __attribute__((address_space(1))) void*)gA,
                                       (__attribute__((address_space(3))) void*)(As + ldsoff),
                                       16, 0, 0);
      __builtin_amdgcn_global_load_lds((const __attribute__((address_space(1))) void*)gB,
                                       (__attribute__((address_space(3))) void*)(Bs + ldsoff),
                                       16, 0, 0);
    }
    __syncthreads();
#pragma unroll
    for (int ki = 0; ki < 64; ki += 32) {
      short8 af[4], bf[4];
#pragma unroll
      for (int f = 0; f < 4; ++f) {
        af[f] = *(const short8*)(As + (wm * 64 + f * 16 + mrow) * 64 + ki + kq);
        bf[f] = *(const short8*)(Bs + (wn * 64 + f * 16 + mrow) * 64 + ki + kq);
      }
#pragma unroll
      for (int fm = 0; fm < 4; ++fm)
#pragma unroll
        for (int fn = 0; fn < 4; ++fn)
          acc[fm][fn] = __builtin_amdgcn_mfma_f32_16x16x32_bf16(af[fm], bf[fn], acc[fm][fn], 0, 0, 0);
    }
  }

  // epilogue: C/D layout col=lane&15, row=(lane>>4)*4+reg
  float*          Cf = (float*)Cout          + (size_t)mz * sC;
  unsigned short* Cb = (unsigned short*)Cout + (size_t)mz * sC;
  const int rq = (lane >> 4) << 2;
  const int cl = lane & 15;
#pragma unroll
  for (int fm = 0; fm < 4; ++fm) {
#pragma unroll
    for (int fn = 0; fn < 4; ++fn) {
      const int cc = col0 + wn * 64 + fn * 16 + cl;
      const float bv = bias[cc];
#pragma unroll
      for (int r = 0; r < 4; ++r) {
        const int rr = row0 + wm * 64 + fm * 16 + rq + r;
        float v = acc[fm][fn][r] + bv;
        if (EPI == 2) {
          Cf[(size_t)rr * N + cc] = 1.0f / (1.0f + __expf(-v));
        } else {
          if (EPI == 1) v = gelu_exact(v);
          Cb[(size_t)rr * N + cc] = f2bf(v);
        }
      }
    }
  }
}

// ---------------- Grouped LayerNorm(+bias already added) + exact GELU, rows of length H_ --
// grid: (B_, M_) blocks, 256 threads; each thread owns 4 consecutive elements.
__global__ void ln_gelu(const unsigned short* __restrict__ in, const float* __restrict__ g,
                        const float* __restrict__ bb, unsigned short* __restrict__ out) {
  const int m = blockIdx.y;
  in  += (size_t)m * B_ * H_;
  out += (size_t)m * B_ * H_;
  g   += (size_t)m * H_;
  bb  += (size_t)m * H_;
  const int row = blockIdx.x;
  const int tid = threadIdx.x;
  const unsigned short* rp = in + (size_t)row * H_;
  uint2 u = ((const uint2*)rp)[tid];
  float x0 = bf2f(u.x & 0xffffu);
  float x1 = bf2f(u.x >> 16);
  float x2 = bf2f(u.y & 0xffffu);
  float x3 = bf2f(u.y >> 16);

  float s  = x0 + x1 + x2 + x3;
  float s2 = x0 * x0 + x1 * x1 + x2 * x2 + x3 * x3;
#pragma unroll
  for (int o = 32; o > 0; o >>= 1) {
    s  += __shfl_down(s, o);
    s2 += __shfl_down(s2, o);
  }
  __shared__ float red[10];
  const int w = tid >> 6;
  if ((tid & 63) == 0) { red[w] = s; red[4 + w] = s2; }
  __syncthreads();
  if (tid == 0) {
    float ts = red[0] + red[1] + red[2] + red[3];
    float t2 = red[4] + red[5] + red[6] + red[7];
    float mean = ts * (1.0f / H_);
    float var  = t2 * (1.0f / H_) - mean * mean;
    red[8] = mean;
    red[9] = rsqrtf(var + 1e-5f);
  }
  __syncthreads();
  const float mean = red[8], rstd = red[9];
  const int col = tid * 4;
  float y0 = gelu_exact((x0 - mean) * rstd * g[col + 0] + bb[col + 0]);
  float y1 = gelu_exact((x1 - mean) * rstd * g[col + 1] + bb[col + 1]);
  float y2 = gelu_exact((x2 - mean) * rstd * g[col + 2] + bb[col + 2]);
  float y3 = gelu_exact((x3 - mean) * rstd * g[col + 3] + bb[col + 3]);
  ushort4 o;
  o.x = f2bf(y0); o.y = f2bf(y1); o.z = f2bf(y2); o.w = f2bf(y3);
  ((ushort4*)(out + (size_t)row * H_))[tid] = o;
}

extern "C" void kernel_launch(void* const* d_in, const int* in_sizes, int n_in,
                              void* d_out, int out_size, void* d_ws, size_t ws_size,
                              hipStream_t stream) {
  const float* x   = (const float*)d_in[0];
  const float* ipw = (const float*)d_in[1];
  const float* ipb = (const float*)d_in[2];
  const float* opw = (const float*)d_in[3];
  const float* opb = (const float*)d_in[4];
  const float* W1  = (const float*)d_in[5];
  const float* b1  = (const float*)d_in[6];
  const float* lng = (const float*)d_in[7];
  const float* lnb = (const float*)d_in[8];
  const float* W2  = (const float*)d_in[9];
  const float* b2  = (const float*)d_in[10];
  const float* W3  = (const float*)d_in[11];
  const float* b3  = (const float*)d_in[12];
  float* out = (float*)d_out;

  char* p = (char*)d_ws;
  auto take = [&](size_t bytes) { void* q = (void*)p; p += (bytes + 255) & ~(size_t)255; return q; };
  unsigned short* xb  = (unsigned short*)take((size_t)B_ * D_ * 2);        // x bf16
  unsigned short* wvb = (unsigned short*)take((size_t)D_ * D_ * 2);        // v-proj rows of in_proj_w [N,K]
  unsigned short* wob = (unsigned short*)take((size_t)D_ * D_ * 2);        // out_proj_w [N,K]
  unsigned short* w1t = (unsigned short*)take((size_t)M_ * H_ * D_ * 2);   // [m][H][D]
  unsigned short* w2t = (unsigned short*)take((size_t)M_ * H2_ * H_ * 2);  // [m][H2][H]
  unsigned short* w3t = (unsigned short*)take((size_t)M_ * D_ * H2_ * 2);  // [m][D][H2]
  unsigned short* vb  = (unsigned short*)take((size_t)B_ * D_ * 2);
  unsigned short* ab  = (unsigned short*)take((size_t)B_ * D_ * 2);
  unsigned short* h1p = (unsigned short*)take((size_t)M_ * B_ * H_ * 2);   // [m][B][H]
  unsigned short* h1a = (unsigned short*)take((size_t)M_ * B_ * H_ * 2);   // [m][B][H]
  unsigned short* h2b = (unsigned short*)take((size_t)M_ * B_ * H2_ * 2);  // [m][B][H2]

  // --- weight/input conversions (run every call; ws is re-poisoned) ---
  cast_f32_bf16<<<dim3((B_ * D_ / 4 + 255) / 256), 256, 0, stream>>>(x, xb, B_ * D_ / 4);
  cast_f32_bf16<<<dim3((D_ * D_ / 4 + 255) / 256), 256, 0, stream>>>(ipw + 2 * D_ * D_, wvb, D_ * D_ / 4);
  cast_f32_bf16<<<dim3((D_ * D_ / 4 + 255) / 256), 256, 0, stream>>>(opw, wob, D_ * D_ / 4);
  transpose_cast<<<dim3(D_ / 32, H_ / 32, M_), dim3(32, 8), 0, stream>>>(W1, w1t, D_, H_);
  transpose_cast<<<dim3(H_ / 32, H2_ / 32, M_), dim3(32, 8), 0, stream>>>(W2, w2t, H_, H2_);
  transpose_cast<<<dim3(H2_ / 32, D_ / 32, M_), dim3(32, 8), 0, stream>>>(W3, w3t, H2_, D_);

  // --- attention: softmax over kv_len=1 is identically 1 -> attn = v; skip q,k ---
  gemm_bt<0><<<dim3(B_ / 128, D_ / 128, 1), 256, 0, stream>>>(
      xb, wvb, ipb + 2 * D_, vb, B_, D_, D_, 0, 0, 0, 0);
  gemm_bt<0><<<dim3(B_ / 128, D_ / 128, 1), 256, 0, stream>>>(
      vb, wob, opb, ab, B_, D_, D_, 0, 0, 0, 0);

  // --- 15 mask MLPs, batched over grid.z (masks are independent) ---
  // GEMM1: h1p[m] = ab @ W1[m]^T + b1[m]   (A shared across z: sA = 0)
  gemm_bt<0><<<dim3(B_ / 128, H_ / 128, M_), 256, 0, stream>>>(
      ab, w1t, b1, h1p, B_, H_, D_,
      0, (long)H_ * D_, (long)H_, (long)B_ * H_);
  // LN + GELU for all masks
  ln_gelu<<<dim3(B_, M_), 256, 0, stream>>>(h1p, lng, lnb, h1a);
  // GEMM2: h2b[m] = gelu(h1a[m] @ W2[m]^T + b2[m])
  gemm_bt<1><<<dim3(B_ / 128, H2_ / 128, M_), 256, 0, stream>>>(
      h1a, w2t, b2, h2b, B_, H2_, H_,
      (long)B_ * H_, (long)H2_ * H_, (long)H2_, (long)B_ * H2_);
  // GEMM3: out[m] = sigmoid(h2b[m] @ W3[m]^T + b3[m])  (fp32 out)
  gemm_bt<2><<<dim3(B_ / 128, D_ / 128, M_), 256, 0, stream>>>(
      h2b, w3t, b3, out, B_, D_, H2_,
      (long)B_ * H2_, (long)D_ * H2_, (long)D_, (long)B_ * D_);
}